// Round 1
// baseline (9154.470 us; speedup 1.0000x reference)
//
#include <hip/hip_runtime.h>
#include <math.h>

#define T_ 4096
#define D_ 1024
#define H_ 16
#define DH_ 64
#define E_ 8
#define CAP_ 1024
#define MLP_ 4096
#define HOPS_ 3

// ---------------------------------------------------------------- embed
__global__ __launch_bounds__(256) void embed_kernel(
    const int* __restrict__ ids, const float* __restrict__ ew, float* __restrict__ h)
{
  const int t = blockIdx.x;
  const int id = ids[t];
  const int c = threadIdx.x * 4;
  *(float4*)(h + (size_t)t * D_ + c) = *(const float4*)(ew + (size_t)id * D_ + c);
}

// ---------------------------------------------------------------- router (one wave per token)
__global__ __launch_bounds__(64) void router_kernel(
    const float* __restrict__ h, const float* __restrict__ rw,
    float* __restrict__ probs, float* __restrict__ gmask)
{
  const int t = blockIdx.x;
  const int lane = threadIdx.x;
  __shared__ float hs[D_];
  #pragma unroll
  for (int j = 0; j < 4; ++j)
    *(float4*)&hs[lane * 4 + j * 256] = *(const float4*)(h + (size_t)t * D_ + lane * 4 + j * 256);
  __syncthreads();
  float l9[9];
  #pragma unroll
  for (int e = 0; e < 9; ++e) {
    float s = 0.0f;
    for (int i = lane; i < D_; i += 64) s += hs[i] * rw[e * D_ + i];
    #pragma unroll
    for (int off = 32; off > 0; off >>= 1) s += __shfl_down(s, off);
    l9[e] = s;  // valid on lane 0
  }
  if (lane == 0) {
    float m = l9[0];
    #pragma unroll
    for (int e = 1; e < 9; ++e) m = fmaxf(m, l9[e]);
    float sum = 0.0f;
    float ex[9];
    #pragma unroll
    for (int e = 0; e < 9; ++e) { ex[e] = expf(l9[e] - m); sum += ex[e]; }
    const float inv = 1.0f / sum;
    // top-2 of logits; ties -> lower index (matches lax.top_k)
    int b1 = 0;
    #pragma unroll
    for (int e = 1; e < 9; ++e) if (l9[e] > l9[b1]) b1 = e;
    int b2 = (b1 == 0) ? 1 : 0;
    #pragma unroll
    for (int e = 0; e < 9; ++e) if (e != b1 && e != b2 && l9[e] > l9[b2]) b2 = e;
    #pragma unroll
    for (int e = 0; e < 8; ++e) {
      const float pe = ex[e] * inv;
      probs[t * 8 + e] = pe;
      gmask[(size_t)e * T_ + t] = (e == b1 || e == b2) ? pe : -1e30f;
    }
  }
}

// ---------------------------------------------------------------- zero rho/cnt
__global__ __launch_bounds__(256) void zero_kernel(float* __restrict__ rho, int* __restrict__ cnt)
{
  const int i = blockIdx.x * 256 + threadIdx.x;
  if (i < T_) rho[i] = 0.0f;
  if (i < E_) cnt[i] = 0;
}

// ---------------------------------------------------------------- capacity select (rank-based)
__global__ __launch_bounds__(256) void select_kernel(
    const float* __restrict__ gmask, const float* __restrict__ probs,
    int* __restrict__ idx, int* __restrict__ cnt, float* __restrict__ rho)
{
  __shared__ float row[T_];
  const int e = blockIdx.y;
  const int tid = threadIdx.x;
  const float* gr = gmask + (size_t)e * T_;
  #pragma unroll
  for (int j = 0; j < 16; ++j) row[tid + 256 * j] = gr[tid + 256 * j];
  __syncthreads();
  const int t = blockIdx.x * 256 + tid;
  const float g = row[t];
  if (g > -1e29f) {
    int rank = 0;
    for (int tt = 0; tt < T_; ++tt) {
      const float gg = row[tt];
      rank += (gg > g) || (gg == g && tt < t);
    }
    if (rank < CAP_) {
      const int pos = atomicAdd(&cnt[e], 1);
      idx[e * CAP_ + pos] = t;
      atomicAdd(&rho[t], probs[t * 8 + e]);
    }
  }
}

// ---------------------------------------------------------------- gather (zero padding rows)
__global__ __launch_bounds__(256) void gather_kernel(
    const float* __restrict__ h, const int* __restrict__ idx, const int* __restrict__ cnt,
    float* __restrict__ xin)
{
  const int c = blockIdx.x, e = blockIdx.y;
  const int c4 = threadIdx.x * 4;
  float4* dst = (float4*)(xin + ((size_t)e * CAP_ + c) * D_ + c4);
  if (c < cnt[e]) {
    const int t = idx[e * CAP_ + c];
    *dst = *(const float4*)(h + (size_t)t * D_ + c4);
  } else {
    float4 z; z.x = z.y = z.z = z.w = 0.0f;
    *dst = z;
  }
}

// ---------------------------------------------------------------- f32 tiled GEMM (row-major A,B,C)
__device__ __forceinline__ float gelu_tanh(float x)
{
  const float x3 = x * x * x;
  return 0.5f * x * (1.0f + tanhf(0.7978845608028654f * (x + 0.044715f * x3)));
}

template <int EPI>
__global__ __launch_bounds__(256) void gemm_f32(
    const float* __restrict__ Abase, const float* __restrict__ Bbase, float* __restrict__ Cbase,
    int M, int N, int K, long sA, long sB, long sC)
{
  const float* A = Abase + (size_t)blockIdx.z * (size_t)sA;
  const float* B = Bbase + (size_t)blockIdx.z * (size_t)sB;
  float* C = Cbase + (size_t)blockIdx.z * (size_t)sC;
  __shared__ float As[16][64];
  __shared__ float Bs[16][64];
  const int tid = threadIdx.x;
  const int tx = tid & 15;
  const int ty = tid >> 4;
  const int m0 = blockIdx.y * 64;
  const int n0 = blockIdx.x * 64;
  const int am = tid >> 2;
  const int ak = (tid & 3) << 2;
  const int bk = tid >> 4;
  const int bn = (tid & 15) << 2;
  float acc[4][4];
  #pragma unroll
  for (int i = 0; i < 4; ++i)
    #pragma unroll
    for (int j = 0; j < 4; ++j) acc[i][j] = 0.0f;
  for (int k0 = 0; k0 < K; k0 += 16) {
    const float4 a4 = *(const float4*)(A + (size_t)(m0 + am) * K + (k0 + ak));
    const float4 b4 = *(const float4*)(B + (size_t)(k0 + bk) * N + (n0 + bn));
    __syncthreads();
    As[ak + 0][am] = a4.x; As[ak + 1][am] = a4.y; As[ak + 2][am] = a4.z; As[ak + 3][am] = a4.w;
    *(float4*)&Bs[bk][bn] = b4;
    __syncthreads();
    #pragma unroll
    for (int kk = 0; kk < 16; ++kk) {
      const float4 av = *(const float4*)&As[kk][ty << 2];
      const float4 bv = *(const float4*)&Bs[kk][tx << 2];
      const float a_[4] = {av.x, av.y, av.z, av.w};
      const float b_[4] = {bv.x, bv.y, bv.z, bv.w};
      #pragma unroll
      for (int i = 0; i < 4; ++i)
        #pragma unroll
        for (int j = 0; j < 4; ++j) acc[i][j] += a_[i] * b_[j];
    }
  }
  #pragma unroll
  for (int i = 0; i < 4; ++i) {
    float4 o;
    if (EPI == 1) {
      o.x = gelu_tanh(acc[i][0]); o.y = gelu_tanh(acc[i][1]);
      o.z = gelu_tanh(acc[i][2]); o.w = gelu_tanh(acc[i][3]);
    } else {
      o.x = acc[i][0]; o.y = acc[i][1]; o.z = acc[i][2]; o.w = acc[i][3];
    }
    *(float4*)(C + (size_t)(m0 + (ty << 2) + i) * N + n0 + (tx << 2)) = o;
  }
}

// ---------------------------------------------------------------- RoPE (in-place on q,k; real rows only)
__global__ __launch_bounds__(256) void rope_kernel(
    float* __restrict__ q, float* __restrict__ k,
    const int* __restrict__ idx, const int* __restrict__ cnt)
{
  const int c = blockIdx.x, g = blockIdx.y;
  const int e = 2 * g;
  if (c >= cnt[e]) return;
  const int t = idx[e * CAP_ + c];
  const int tid = threadIdx.x;
  const int hh = tid >> 4;
  const int pp = tid & 15;
  const size_t base = ((size_t)g * CAP_ + c) * D_ + hh * DH_;
  const float tf = (float)t;
  #pragma unroll
  for (int u = 0; u < 2; ++u) {
    const int i = pp * 2 + u;  // 0..31
    const float invf = (float)::pow(10000.0, -(double)i / 32.0);  // correctly-rounded f32 inv
    const float ang = tf * invf;                                   // f32 product (matches np)
    const float cs = (float)::cos((double)ang);
    const float sn = (float)::sin((double)ang);
    const float q0 = q[base + i], q1 = q[base + i + 32];
    q[base + i]      = q0 * cs - q1 * sn;
    q[base + i + 32] = q1 * cs + q0 * sn;
    const float k0 = k[base + i], k1 = k[base + i + 32];
    k[base + i]      = k0 * cs - k1 * sn;
    k[base + i + 32] = k1 * cs + k0 * sn;
  }
}

// ---------------------------------------------------------------- flash attention (16 queries/block)
__global__ __launch_bounds__(256) void flash_kernel(
    const float* __restrict__ qg, const float* __restrict__ kg,
    const float* __restrict__ vg, float* __restrict__ og)
{
  const int g = blockIdx.z, hh = blockIdx.y, qb = blockIdx.x;
  const size_t base = (size_t)g * CAP_ * D_ + hh * DH_;
  const float* Q = qg + base;
  const float* Kp = kg + base;
  const float* Vp = vg + base;
  float* O = og + base;
  __shared__ float Qs[16][65];
  __shared__ float Ks[64][65];
  __shared__ float Vs[64][64];
  __shared__ float Ss[16][65];
  __shared__ float red[16][17];
  __shared__ float rowm[16], rowl[16], rowa[16], rownm[16];
  const int tid = threadIdx.x;
  const int qi = tid >> 4;
  const int di = tid & 15;
  {
    const int r = tid >> 4;
    const int cc = (tid & 15) * 4;
    const float4 q4 = *(const float4*)(Q + (size_t)(qb * 16 + r) * D_ + cc);
    Qs[r][cc] = q4.x; Qs[r][cc + 1] = q4.y; Qs[r][cc + 2] = q4.z; Qs[r][cc + 3] = q4.w;
  }
  if (tid < 16) { rowm[tid] = -1e30f; rowl[tid] = 0.0f; }
  float4 acc; acc.x = acc.y = acc.z = acc.w = 0.0f;
  __syncthreads();
  for (int kt = 0; kt < 16; ++kt) {
    #pragma unroll
    for (int jj = 0; jj < 4; ++jj) {
      const int r = jj * 16 + (tid >> 4);
      const int cc = (tid & 15) * 4;
      const float4 k4 = *(const float4*)(Kp + (size_t)(kt * 64 + r) * D_ + cc);
      Ks[r][cc] = k4.x; Ks[r][cc + 1] = k4.y; Ks[r][cc + 2] = k4.z; Ks[r][cc + 3] = k4.w;
      *(float4*)&Vs[r][cc] = *(const float4*)(Vp + (size_t)(kt * 64 + r) * D_ + cc);
    }
    __syncthreads();
    // scores: 4 keys per thread
    float sv[4] = {0.0f, 0.0f, 0.0f, 0.0f};
    #pragma unroll 8
    for (int d = 0; d < 64; ++d) {
      const float qd = Qs[qi][d];
      #pragma unroll
      for (int j = 0; j < 4; ++j) sv[j] += qd * Ks[di * 4 + j][d];
    }
    float smax = -1e30f;
    #pragma unroll
    for (int j = 0; j < 4; ++j) { sv[j] *= 0.125f; smax = fmaxf(smax, sv[j]); }
    red[qi][di] = smax;
    __syncthreads();
    if (di == 0) {
      float tm = red[qi][0];
      #pragma unroll
      for (int j2 = 1; j2 < 16; ++j2) tm = fmaxf(tm, red[qi][j2]);
      const float nm = fmaxf(rowm[qi], tm);
      rowa[qi] = expf(rowm[qi] - nm);
      rownm[qi] = nm;
    }
    __syncthreads();
    const float nm = rownm[qi];
    float psum = 0.0f;
    #pragma unroll
    for (int j = 0; j < 4; ++j) {
      const float pv = expf(sv[j] - nm);
      Ss[qi][di * 4 + j] = pv;
      psum += pv;
    }
    red[qi][di] = psum;
    __syncthreads();
    if (di == 0) {
      float s = 0.0f;
      #pragma unroll
      for (int j2 = 0; j2 < 16; ++j2) s += red[qi][j2];
      rowl[qi] = rowl[qi] * rowa[qi] + s;
      rowm[qi] = rownm[qi];
    }
    const float aa = rowa[qi];
    acc.x *= aa; acc.y *= aa; acc.z *= aa; acc.w *= aa;
    #pragma unroll 8
    for (int k2 = 0; k2 < 64; ++k2) {
      const float pv = Ss[qi][k2];
      const float4 vv = *(const float4*)&Vs[k2][di * 4];
      acc.x += pv * vv.x; acc.y += pv * vv.y; acc.z += pv * vv.z; acc.w += pv * vv.w;
    }
    __syncthreads();
  }
  const float invl = 1.0f / rowl[qi];
  float4 o;
  o.x = acc.x * invl; o.y = acc.y * invl; o.z = acc.z * invl; o.w = acc.w * invl;
  *(float4*)(O + (size_t)(qb * 16 + qi) * D_ + di * 4) = o;
}

// ---------------------------------------------------------------- hnew = h*(1-rho)
__global__ __launch_bounds__(256) void initnew_kernel(
    const float* __restrict__ h, const float* __restrict__ rho, float* __restrict__ hn)
{
  const int t = blockIdx.x;
  const float f = 1.0f - rho[t];
  const int c = threadIdx.x * 4;
  float4 x = *(const float4*)(h + (size_t)t * D_ + c);
  x.x *= f; x.y *= f; x.z *= f; x.w *= f;
  *(float4*)(hn + (size_t)t * D_ + c) = x;
}

// ---------------------------------------------------------------- scatter expert_out back
__global__ __launch_bounds__(256) void scatter_kernel(
    const float* __restrict__ eo, const int* __restrict__ idx, const int* __restrict__ cnt,
    const float* __restrict__ probs, float* __restrict__ hn)
{
  const int c = blockIdx.x, e = blockIdx.y;
  if (c >= cnt[e]) return;
  const int t = idx[e * CAP_ + c];
  const float w = probs[t * 8 + e];
  const float* src = eo + ((size_t)e * CAP_ + c) * D_;
  float* dst = hn + (size_t)t * D_;
  const int c4 = threadIdx.x * 4;
  #pragma unroll
  for (int j = 0; j < 4; ++j) atomicAdd(dst + c4 + j, src[c4 + j] * w);
}

// ---------------------------------------------------------------- RMS norm
__global__ __launch_bounds__(256) void rms_kernel(
    const float* __restrict__ h, const float* __restrict__ w, float* __restrict__ out)
{
  const int t = blockIdx.x;
  const int c = threadIdx.x * 4;
  const float4 x = *(const float4*)(h + (size_t)t * D_ + c);
  float ss = x.x * x.x + x.y * x.y + x.z * x.z + x.w * x.w;
  #pragma unroll
  for (int off = 32; off > 0; off >>= 1) ss += __shfl_down(ss, off);
  __shared__ float wsum[4];
  __shared__ float sscale;
  const int lane = threadIdx.x & 63, wv = threadIdx.x >> 6;
  if (lane == 0) wsum[wv] = ss;
  __syncthreads();
  if (threadIdx.x == 0) {
    const float s = wsum[0] + wsum[1] + wsum[2] + wsum[3];
    sscale = 1.0f / sqrtf(s * (1.0f / (float)D_) + 1e-6f);
  }
  __syncthreads();
  const float sc = sscale;
  const float4 w4 = *(const float4*)(w + c);
  float4 o;
  o.x = x.x * sc * w4.x; o.y = x.y * sc * w4.y; o.z = x.z * sc * w4.z; o.w = x.w * sc * w4.w;
  *(float4*)(out + (size_t)t * D_ + c) = o;
}

// ================================================================ host
extern "C" void kernel_launch(void* const* d_in, const int* in_sizes, int n_in,
                              void* d_out, int out_size, void* d_ws, size_t ws_size,
                              hipStream_t stream)
{
  (void)in_sizes; (void)n_in; (void)out_size; (void)ws_size;
  const int* ids = (const int*)d_in[0];
  const float* embed_w = (const float*)d_in[1];
  const float* router_w = (const float*)d_in[2];
  const float* wq = (const float*)d_in[3];
  const float* wk = (const float*)d_in[4];
  const float* wv = (const float*)d_in[5];
  const float* wo = (const float*)d_in[6];
  const float* w1 = (const float*)d_in[7];
  const float* w2 = (const float*)d_in[8];
  const float* lnw = (const float*)d_in[9];
  float* out = (float*)d_out;

  float* p = (float*)d_ws;
  const size_t TD = (size_t)T_ * D_;
  float* hA = p;    p += TD;
  float* hB = p;    p += TD;
  float* probs = p; p += (size_t)T_ * E_;
  float* gmask = p; p += (size_t)E_ * T_;
  float* rho = p;   p += T_;
  int* idx = (int*)p;   p += E_ * CAP_;
  int* cnt = (int*)p;   p += 16;
  float* xin = p;  p += (size_t)E_ * CAP_ * D_;
  float* qb = p;   p += (size_t)4 * CAP_ * D_;
  float* kb = p;   p += (size_t)4 * CAP_ * D_;
  float* vb = p;   p += (size_t)4 * CAP_ * D_;
  float* ao = p;   p += (size_t)4 * CAP_ * D_;
  float* mid = p;  p += (size_t)CAP_ * MLP_;
  float* eo = p;   p += (size_t)E_ * CAP_ * D_;

  embed_kernel<<<T_, 256, 0, stream>>>(ids, embed_w, hA);
  float* cur = hA;
  float* nxt = hB;
  for (int hop = 0; hop < HOPS_; ++hop) {
    router_kernel<<<T_, 64, 0, stream>>>(cur, router_w + (size_t)hop * 9 * D_, probs, gmask);
    zero_kernel<<<16, 256, 0, stream>>>(rho, cnt);
    select_kernel<<<dim3(16, 8), 256, 0, stream>>>(gmask, probs, idx, cnt, rho);
    gather_kernel<<<dim3(CAP_, E_), 256, 0, stream>>>(cur, idx, cnt, xin);
    // QKV projections (batched over 4 attention groups; A = xin rows of experts 0,2,4,6)
    gemm_f32<0><<<dim3(16, 16, 4), 256, 0, stream>>>(xin, wq, qb, CAP_, D_, D_,
        (long)2 * CAP_ * D_, (long)D_ * D_, (long)CAP_ * D_);
    gemm_f32<0><<<dim3(16, 16, 4), 256, 0, stream>>>(xin, wk, kb, CAP_, D_, D_,
        (long)2 * CAP_ * D_, (long)D_ * D_, (long)CAP_ * D_);
    gemm_f32<0><<<dim3(16, 16, 4), 256, 0, stream>>>(xin, wv, vb, CAP_, D_, D_,
        (long)2 * CAP_ * D_, (long)D_ * D_, (long)CAP_ * D_);
    rope_kernel<<<dim3(CAP_, 4), 256, 0, stream>>>(qb, kb, idx, cnt);
    flash_kernel<<<dim3(64, 16, 4), 256, 0, stream>>>(qb, kb, vb, ao);
    // output projection into expert_out slots 0,2,4,6
    gemm_f32<0><<<dim3(16, 16, 4), 256, 0, stream>>>(ao, wo, eo, CAP_, D_, D_,
        (long)CAP_ * D_, (long)D_ * D_, (long)2 * CAP_ * D_);
    // FFN experts 1,3,5,7 (sequential per group to bound workspace)
    for (int g = 0; g < 4; ++g) {
      gemm_f32<1><<<dim3(64, 16, 1), 256, 0, stream>>>(
          xin + ((size_t)(2 * g + 1)) * CAP_ * D_, w1 + (size_t)g * D_ * MLP_, mid,
          CAP_, MLP_, D_, 0, 0, 0);
      gemm_f32<0><<<dim3(16, 16, 1), 256, 0, stream>>>(
          mid, w2 + (size_t)g * MLP_ * D_, eo + ((size_t)(2 * g + 1)) * CAP_ * D_,
          CAP_, D_, MLP_, 0, 0, 0);
    }
    initnew_kernel<<<T_, 256, 0, stream>>>(cur, rho, nxt);
    scatter_kernel<<<dim3(CAP_, E_), 256, 0, stream>>>(eo, idx, cnt, probs, nxt);
    float* tmp = cur; cur = nxt; nxt = tmp;
  }
  rms_kernel<<<T_, 256, 0, stream>>>(cur, lnw, out);
}

// Round 2
// 4579.427 us; speedup vs baseline: 1.9990x; 1.9990x over previous
//
#include <hip/hip_runtime.h>
#include <math.h>

#define T_ 4096
#define D_ 1024
#define H_ 16
#define DH_ 64
#define E_ 8
#define CAP_ 1024
#define MLP_ 4096
#define HOPS_ 3

// ================================================================ embed
__global__ __launch_bounds__(256) void embed_kernel(
    const int* __restrict__ ids, const float* __restrict__ ew, float* __restrict__ h)
{
  const int t = blockIdx.x;
  const int id = ids[t];
  const int c = threadIdx.x * 4;
  *(float4*)(h + (size_t)t * D_ + c) = *(const float4*)(ew + (size_t)id * D_ + c);
}

// ================================================================ router
__global__ __launch_bounds__(64) void router_kernel(
    const float* __restrict__ h, const float* __restrict__ rw,
    float* __restrict__ probs, float* __restrict__ gmask)
{
  const int t = blockIdx.x;
  const int lane = threadIdx.x;
  __shared__ float hs[D_];
  #pragma unroll
  for (int j = 0; j < 4; ++j)
    *(float4*)&hs[lane * 4 + j * 256] = *(const float4*)(h + (size_t)t * D_ + lane * 4 + j * 256);
  __syncthreads();
  float l9[9];
  #pragma unroll
  for (int e = 0; e < 9; ++e) {
    float s = 0.0f;
    for (int i = lane; i < D_; i += 64) s += hs[i] * rw[e * D_ + i];
    #pragma unroll
    for (int off = 32; off > 0; off >>= 1) s += __shfl_down(s, off);
    l9[e] = s;
  }
  if (lane == 0) {
    float m = l9[0];
    #pragma unroll
    for (int e = 1; e < 9; ++e) m = fmaxf(m, l9[e]);
    float sum = 0.0f;
    float ex[9];
    #pragma unroll
    for (int e = 0; e < 9; ++e) { ex[e] = expf(l9[e] - m); sum += ex[e]; }
    const float inv = 1.0f / sum;
    int b1 = 0;
    #pragma unroll
    for (int e = 1; e < 9; ++e) if (l9[e] > l9[b1]) b1 = e;
    int b2 = (b1 == 0) ? 1 : 0;
    #pragma unroll
    for (int e = 0; e < 9; ++e) if (e != b1 && e != b2 && l9[e] > l9[b2]) b2 = e;
    #pragma unroll
    for (int e = 0; e < 8; ++e) {
      const float pe = ex[e] * inv;
      probs[t * 8 + e] = pe;
      gmask[(size_t)e * T_ + t] = (e == b1 || e == b2) ? pe : -1e30f;
    }
  }
}

// ================================================================ zero
__global__ __launch_bounds__(256) void zero_kernel(float* __restrict__ rho, int* __restrict__ cnt)
{
  const int i = blockIdx.x * 256 + threadIdx.x;
  if (i < T_) rho[i] = 0.0f;
  if (i < E_) cnt[i] = 0;
}

// ================================================================ capacity select (rank-based)
__global__ __launch_bounds__(256) void select_kernel(
    const float* __restrict__ gmask, const float* __restrict__ probs,
    int* __restrict__ idx, int* __restrict__ cnt, float* __restrict__ rho)
{
  __shared__ float row[T_];
  const int e = blockIdx.y;
  const int tid = threadIdx.x;
  const float* gr = gmask + (size_t)e * T_;
  #pragma unroll
  for (int j = 0; j < 16; ++j) row[tid + 256 * j] = gr[tid + 256 * j];
  __syncthreads();
  const int t = blockIdx.x * 256 + tid;
  const float g = row[t];
  if (g > -1e29f) {
    int rank = 0;
    for (int tt = 0; tt < T_; ++tt) {
      const float gg = row[tt];
      rank += (gg > g) || (gg == g && tt < t);
    }
    if (rank < CAP_) {
      const int pos = atomicAdd(&cnt[e], 1);
      idx[e * CAP_ + pos] = t;
      atomicAdd(&rho[t], probs[t * 8 + e]);
    }
  }
}

// ================================================================ gather
__global__ __launch_bounds__(256) void gather_kernel(
    const float* __restrict__ h, const int* __restrict__ idx, const int* __restrict__ cnt,
    float* __restrict__ xin)
{
  const int c = blockIdx.x, e = blockIdx.y;
  const int c4 = threadIdx.x * 4;
  float4* dst = (float4*)(xin + ((size_t)e * CAP_ + c) * D_ + c4);
  if (c < cnt[e]) {
    const int t = idx[e * CAP_ + c];
    *dst = *(const float4*)(h + (size_t)t * D_ + c4);
  } else {
    float4 z; z.x = z.y = z.z = z.w = 0.0f;
    *dst = z;
  }
}

// ================================================================ split-bf16 MFMA GEMM
// C(MxN) = A(MxK, row-major f32) * B(KxN, row-major f32)
// a = a_hi + a_lo (bf16 truncation split); P ~= ah*bh + ah*bl + al*bh  (rel err ~2^-16)
typedef __bf16 bf16x8 __attribute__((ext_vector_type(8)));
typedef float f32x4v __attribute__((ext_vector_type(4)));

union FragU { uint2 u2[2]; bf16x8 v; };

#define BM 128
#define BN 128
#define BK 32
#define LDT 36  // shorts per 32-k row (padded; 72B, 8B-aligned)

__device__ __forceinline__ float gelu_tanh(float x)
{
  const float x3 = x * x * x;
  return 0.5f * x * (1.0f + tanhf(0.7978845608028654f * (x + 0.044715f * x3)));
}

__device__ __forceinline__ unsigned pack_hi2(unsigned u0, unsigned u1)
{
  return (u0 >> 16) | (u1 & 0xFFFF0000u);
}

template <int EPI>
__device__ __forceinline__ void gemm_core(
    const float* __restrict__ A, const float* __restrict__ B, float* __restrict__ C,
    int N, int K)
{
  __shared__ unsigned short Ah[BM * LDT];
  __shared__ unsigned short Al[BM * LDT];
  __shared__ unsigned short Bh[BN * LDT];
  __shared__ unsigned short Bl[BN * LDT];

  const int tid = threadIdx.x;
  const int lane = tid & 63;
  const int w = tid >> 6;
  const int wm = w >> 1, wn = w & 1;
  const int m0 = blockIdx.y * BM;
  const int n0 = blockIdx.x * BN;
  const int q = lane >> 4;
  const int l15 = lane & 15;

  // staging maps
  const int a_mo = tid >> 3;       // + t*32 -> m in tile
  const int a_kq = (tid & 7) * 4;  // k offset within BK
  const int b_n = tid & 127;       // n in tile
  const int b_kh = (tid >> 7) * 16;

  f32x4v acc[4][4];
  #pragma unroll
  for (int i = 0; i < 4; ++i)
    #pragma unroll
    for (int j = 0; j < 4; ++j) { acc[i][j][0] = 0.f; acc[i][j][1] = 0.f; acc[i][j][2] = 0.f; acc[i][j][3] = 0.f; }

  float4 a_reg[4];
  float b_reg[16];

  const int nk = K / BK;
  // prologue loads (tile 0)
  #pragma unroll
  for (int t = 0; t < 4; ++t)
    a_reg[t] = *(const float4*)(A + (size_t)(m0 + t * 32 + a_mo) * K + a_kq);
  {
    const float* Bp = B + (size_t)b_kh * N + n0 + b_n;
    #pragma unroll
    for (int i = 0; i < 16; ++i) b_reg[i] = Bp[(size_t)i * N];
  }

  for (int kt = 0; kt < nk; ++kt) {
    __syncthreads();
    // ---- convert + write A tile: [m][k] hi/lo planes
    #pragma unroll
    for (int t = 0; t < 4; ++t) {
      const int m = t * 32 + a_mo;
      const unsigned u0 = __float_as_uint(a_reg[t].x);
      const unsigned u1 = __float_as_uint(a_reg[t].y);
      const unsigned u2 = __float_as_uint(a_reg[t].z);
      const unsigned u3 = __float_as_uint(a_reg[t].w);
      const float l0 = a_reg[t].x - __uint_as_float(u0 & 0xFFFF0000u);
      const float l1 = a_reg[t].y - __uint_as_float(u1 & 0xFFFF0000u);
      const float l2 = a_reg[t].z - __uint_as_float(u2 & 0xFFFF0000u);
      const float l3 = a_reg[t].w - __uint_as_float(u3 & 0xFFFF0000u);
      uint2 hp, lp;
      hp.x = pack_hi2(u0, u1); hp.y = pack_hi2(u2, u3);
      lp.x = pack_hi2(__float_as_uint(l0), __float_as_uint(l1));
      lp.y = pack_hi2(__float_as_uint(l2), __float_as_uint(l3));
      *(uint2*)&Ah[m * LDT + a_kq] = hp;
      *(uint2*)&Al[m * LDT + a_kq] = lp;
    }
    // ---- convert + write B tile transposed: [n][k] hi/lo planes
    #pragma unroll
    for (int i = 0; i < 4; ++i) {
      const float f0 = b_reg[4 * i + 0], f1 = b_reg[4 * i + 1];
      const float f2 = b_reg[4 * i + 2], f3 = b_reg[4 * i + 3];
      const unsigned u0 = __float_as_uint(f0);
      const unsigned u1 = __float_as_uint(f1);
      const unsigned u2 = __float_as_uint(f2);
      const unsigned u3 = __float_as_uint(f3);
      const float l0 = f0 - __uint_as_float(u0 & 0xFFFF0000u);
      const float l1 = f1 - __uint_as_float(u1 & 0xFFFF0000u);
      const float l2 = f2 - __uint_as_float(u2 & 0xFFFF0000u);
      const float l3 = f3 - __uint_as_float(u3 & 0xFFFF0000u);
      uint2 hp, lp;
      hp.x = pack_hi2(u0, u1); hp.y = pack_hi2(u2, u3);
      lp.x = pack_hi2(__float_as_uint(l0), __float_as_uint(l1));
      lp.y = pack_hi2(__float_as_uint(l2), __float_as_uint(l3));
      *(uint2*)&Bh[b_n * LDT + b_kh + 4 * i] = hp;
      *(uint2*)&Bl[b_n * LDT + b_kh + 4 * i] = lp;
    }
    // ---- prefetch next tile while MFMA runs
    if (kt + 1 < nk) {
      const int k0 = (kt + 1) * BK;
      #pragma unroll
      for (int t = 0; t < 4; ++t)
        a_reg[t] = *(const float4*)(A + (size_t)(m0 + t * 32 + a_mo) * K + k0 + a_kq);
      const float* Bp = B + (size_t)(k0 + b_kh) * N + n0 + b_n;
      #pragma unroll
      for (int i = 0; i < 16; ++i) b_reg[i] = Bp[(size_t)i * N];
    }
    __syncthreads();
    // ---- fragments + MFMA
    FragU fa_h[4], fa_l[4], fb_h[4], fb_l[4];
    #pragma unroll
    for (int i = 0; i < 4; ++i) {
      const int m = wm * 64 + i * 16 + l15;
      const unsigned short* pa = &Ah[m * LDT + q * 8];
      const unsigned short* pl = &Al[m * LDT + q * 8];
      fa_h[i].u2[0] = *(const uint2*)pa; fa_h[i].u2[1] = *(const uint2*)(pa + 4);
      fa_l[i].u2[0] = *(const uint2*)pl; fa_l[i].u2[1] = *(const uint2*)(pl + 4);
    }
    #pragma unroll
    for (int j = 0; j < 4; ++j) {
      const int n = wn * 64 + j * 16 + l15;
      const unsigned short* pb = &Bh[n * LDT + q * 8];
      const unsigned short* pl = &Bl[n * LDT + q * 8];
      fb_h[j].u2[0] = *(const uint2*)pb; fb_h[j].u2[1] = *(const uint2*)(pb + 4);
      fb_l[j].u2[0] = *(const uint2*)pl; fb_l[j].u2[1] = *(const uint2*)(pl + 4);
    }
    #pragma unroll
    for (int i = 0; i < 4; ++i)
      #pragma unroll
      for (int j = 0; j < 4; ++j) {
        acc[i][j] = __builtin_amdgcn_mfma_f32_16x16x32_bf16(fa_h[i].v, fb_h[j].v, acc[i][j], 0, 0, 0);
        acc[i][j] = __builtin_amdgcn_mfma_f32_16x16x32_bf16(fa_h[i].v, fb_l[j].v, acc[i][j], 0, 0, 0);
        acc[i][j] = __builtin_amdgcn_mfma_f32_16x16x32_bf16(fa_l[i].v, fb_h[j].v, acc[i][j], 0, 0, 0);
      }
  }
  // ---- epilogue: C/D layout row = 4*quad + reg (M), col = lane&15 (N)
  #pragma unroll
  for (int i = 0; i < 4; ++i)
    #pragma unroll
    for (int j = 0; j < 4; ++j) {
      const int n = n0 + wn * 64 + j * 16 + l15;
      #pragma unroll
      for (int r = 0; r < 4; ++r) {
        const int m = m0 + wm * 64 + i * 16 + q * 4 + r;
        float v = acc[i][j][r];
        if (EPI == 1) v = gelu_tanh(v);
        C[(size_t)m * N + n] = v;
      }
    }
}

template <int EPI>
__global__ __launch_bounds__(256, 2) void gemm_split(
    const float* __restrict__ Abase, const float* __restrict__ Bbase, float* __restrict__ Cbase,
    int N, int K, long sA, long sB, long sC)
{
  const float* A = Abase + (size_t)blockIdx.z * (size_t)sA;
  const float* B = Bbase + (size_t)blockIdx.z * (size_t)sB;
  float* C = Cbase + (size_t)blockIdx.z * (size_t)sC;
  gemm_core<EPI>(A, B, C, N, K);
}

__global__ __launch_bounds__(256, 2) void gemm_qkv(
    const float* __restrict__ xin,
    const float* __restrict__ wq, const float* __restrict__ wk, const float* __restrict__ wv,
    float* __restrict__ qb, float* __restrict__ kb, float* __restrict__ vb)
{
  const int z = blockIdx.z;
  const int g = z & 3;
  const int which = z >> 2;
  const float* A = xin + (size_t)g * 2 * CAP_ * D_;
  const float* B = ((which == 0) ? wq : (which == 1) ? wk : wv) + (size_t)g * D_ * D_;
  float* C = ((which == 0) ? qb : (which == 1) ? kb : vb) + (size_t)g * CAP_ * D_;
  gemm_core<0>(A, B, C, D_, D_);
}

// ================================================================ RoPE
__global__ __launch_bounds__(256) void rope_kernel(
    float* __restrict__ q, float* __restrict__ k,
    const int* __restrict__ idx, const int* __restrict__ cnt)
{
  const int c = blockIdx.x, g = blockIdx.y;
  const int e = 2 * g;
  if (c >= cnt[e]) return;
  const int t = idx[e * CAP_ + c];
  const int tid = threadIdx.x;
  const int hh = tid >> 4;
  const int pp = tid & 15;
  const size_t base = ((size_t)g * CAP_ + c) * D_ + hh * DH_;
  const float tf = (float)t;
  #pragma unroll
  for (int u = 0; u < 2; ++u) {
    const int i = pp * 2 + u;
    const float invf = (float)::pow(10000.0, -(double)i / 32.0);
    const float ang = tf * invf;
    const float cs = (float)::cos((double)ang);
    const float sn = (float)::sin((double)ang);
    const float q0 = q[base + i], q1 = q[base + i + 32];
    q[base + i]      = q0 * cs - q1 * sn;
    q[base + i + 32] = q1 * cs + q0 * sn;
    const float k0 = k[base + i], k1 = k[base + i + 32];
    k[base + i]      = k0 * cs - k1 * sn;
    k[base + i + 32] = k1 * cs + k0 * sn;
  }
}

// ================================================================ flash attention
__global__ __launch_bounds__(256) void flash_kernel(
    const float* __restrict__ qg, const float* __restrict__ kg,
    const float* __restrict__ vg, float* __restrict__ og)
{
  const int g = blockIdx.z, hh = blockIdx.y, qb = blockIdx.x;
  const size_t base = (size_t)g * CAP_ * D_ + hh * DH_;
  const float* Q = qg + base;
  const float* Kp = kg + base;
  const float* Vp = vg + base;
  float* O = og + base;
  __shared__ float Qs[16][65];
  __shared__ float Ks[64][65];
  __shared__ float Vs[64][64];
  __shared__ float Ss[16][65];
  __shared__ float red[16][17];
  __shared__ float rowm[16], rowl[16], rowa[16], rownm[16];
  const int tid = threadIdx.x;
  const int qi = tid >> 4;
  const int di = tid & 15;
  {
    const int r = tid >> 4;
    const int cc = (tid & 15) * 4;
    const float4 q4 = *(const float4*)(Q + (size_t)(qb * 16 + r) * D_ + cc);
    Qs[r][cc] = q4.x; Qs[r][cc + 1] = q4.y; Qs[r][cc + 2] = q4.z; Qs[r][cc + 3] = q4.w;
  }
  if (tid < 16) { rowm[tid] = -1e30f; rowl[tid] = 0.0f; }
  float4 acc; acc.x = acc.y = acc.z = acc.w = 0.0f;
  __syncthreads();
  for (int kt = 0; kt < 16; ++kt) {
    #pragma unroll
    for (int jj = 0; jj < 4; ++jj) {
      const int r = jj * 16 + (tid >> 4);
      const int cc = (tid & 15) * 4;
      const float4 k4 = *(const float4*)(Kp + (size_t)(kt * 64 + r) * D_ + cc);
      Ks[r][cc] = k4.x; Ks[r][cc + 1] = k4.y; Ks[r][cc + 2] = k4.z; Ks[r][cc + 3] = k4.w;
      *(float4*)&Vs[r][cc] = *(const float4*)(Vp + (size_t)(kt * 64 + r) * D_ + cc);
    }
    __syncthreads();
    float sv[4] = {0.0f, 0.0f, 0.0f, 0.0f};
    #pragma unroll 8
    for (int d = 0; d < 64; ++d) {
      const float qd = Qs[qi][d];
      #pragma unroll
      for (int j = 0; j < 4; ++j) sv[j] += qd * Ks[di * 4 + j][d];
    }
    float smax = -1e30f;
    #pragma unroll
    for (int j = 0; j < 4; ++j) { sv[j] *= 0.125f; smax = fmaxf(smax, sv[j]); }
    red[qi][di] = smax;
    __syncthreads();
    if (di == 0) {
      float tm = red[qi][0];
      #pragma unroll
      for (int j2 = 1; j2 < 16; ++j2) tm = fmaxf(tm, red[qi][j2]);
      const float nm = fmaxf(rowm[qi], tm);
      rowa[qi] = expf(rowm[qi] - nm);
      rownm[qi] = nm;
    }
    __syncthreads();
    const float nm = rownm[qi];
    float psum = 0.0f;
    #pragma unroll
    for (int j = 0; j < 4; ++j) {
      const float pv = expf(sv[j] - nm);
      Ss[qi][di * 4 + j] = pv;
      psum += pv;
    }
    red[qi][di] = psum;
    __syncthreads();
    if (di == 0) {
      float s = 0.0f;
      #pragma unroll
      for (int j2 = 0; j2 < 16; ++j2) s += red[qi][j2];
      rowl[qi] = rowl[qi] * rowa[qi] + s;
      rowm[qi] = rownm[qi];
    }
    const float aa = rowa[qi];
    acc.x *= aa; acc.y *= aa; acc.z *= aa; acc.w *= aa;
    #pragma unroll 8
    for (int k2 = 0; k2 < 64; ++k2) {
      const float pv = Ss[qi][k2];
      const float4 vv = *(const float4*)&Vs[k2][di * 4];
      acc.x += pv * vv.x; acc.y += pv * vv.y; acc.z += pv * vv.z; acc.w += pv * vv.w;
    }
    __syncthreads();
  }
  const float invl = 1.0f / rowl[qi];
  float4 o;
  o.x = acc.x * invl; o.y = acc.y * invl; o.z = acc.z * invl; o.w = acc.w * invl;
  *(float4*)(O + (size_t)(qb * 16 + qi) * D_ + di * 4) = o;
}

// ================================================================ hnew = h*(1-rho)
__global__ __launch_bounds__(256) void initnew_kernel(
    const float* __restrict__ h, const float* __restrict__ rho, float* __restrict__ hn)
{
  const int t = blockIdx.x;
  const float f = 1.0f - rho[t];
  const int c = threadIdx.x * 4;
  float4 x = *(const float4*)(h + (size_t)t * D_ + c);
  x.x *= f; x.y *= f; x.z *= f; x.w *= f;
  *(float4*)(hn + (size_t)t * D_ + c) = x;
}

// ================================================================ scatter
__global__ __launch_bounds__(256) void scatter_kernel(
    const float* __restrict__ eo, const int* __restrict__ idx, const int* __restrict__ cnt,
    const float* __restrict__ probs, float* __restrict__ hn)
{
  const int c = blockIdx.x, e = blockIdx.y;
  if (c >= cnt[e]) return;
  const int t = idx[e * CAP_ + c];
  const float w = probs[t * 8 + e];
  const float* src = eo + ((size_t)e * CAP_ + c) * D_;
  float* dst = hn + (size_t)t * D_;
  const int c4 = threadIdx.x * 4;
  #pragma unroll
  for (int j = 0; j < 4; ++j) atomicAdd(dst + c4 + j, src[c4 + j] * w);
}

// ================================================================ RMS norm
__global__ __launch_bounds__(256) void rms_kernel(
    const float* __restrict__ h, const float* __restrict__ w, float* __restrict__ out)
{
  const int t = blockIdx.x;
  const int c = threadIdx.x * 4;
  const float4 x = *(const float4*)(h + (size_t)t * D_ + c);
  float ss = x.x * x.x + x.y * x.y + x.z * x.z + x.w * x.w;
  #pragma unroll
  for (int off = 32; off > 0; off >>= 1) ss += __shfl_down(ss, off);
  __shared__ float wsum[4];
  __shared__ float sscale;
  const int lane = threadIdx.x & 63, wv = threadIdx.x >> 6;
  if (lane == 0) wsum[wv] = ss;
  __syncthreads();
  if (threadIdx.x == 0) {
    const float s = wsum[0] + wsum[1] + wsum[2] + wsum[3];
    sscale = 1.0f / sqrtf(s * (1.0f / (float)D_) + 1e-6f);
  }
  __syncthreads();
  const float sc = sscale;
  const float4 w4 = *(const float4*)(w + c);
  float4 o;
  o.x = x.x * sc * w4.x; o.y = x.y * sc * w4.y; o.z = x.z * sc * w4.z; o.w = x.w * sc * w4.w;
  *(float4*)(out + (size_t)t * D_ + c) = o;
}

// ================================================================ host
extern "C" void kernel_launch(void* const* d_in, const int* in_sizes, int n_in,
                              void* d_out, int out_size, void* d_ws, size_t ws_size,
                              hipStream_t stream)
{
  (void)in_sizes; (void)n_in; (void)out_size; (void)ws_size;
  const int* ids = (const int*)d_in[0];
  const float* embed_w = (const float*)d_in[1];
  const float* router_w = (const float*)d_in[2];
  const float* wq = (const float*)d_in[3];
  const float* wk = (const float*)d_in[4];
  const float* wv = (const float*)d_in[5];
  const float* wo = (const float*)d_in[6];
  const float* w1 = (const float*)d_in[7];
  const float* w2 = (const float*)d_in[8];
  const float* lnw = (const float*)d_in[9];
  float* out = (float*)d_out;

  float* p = (float*)d_ws;
  const size_t TD = (size_t)T_ * D_;
  float* hA = p;    p += TD;
  float* hB = p;    p += TD;
  float* probs = p; p += (size_t)T_ * E_;
  float* gmask = p; p += (size_t)E_ * T_;
  float* rho = p;   p += T_;
  int* idx = (int*)p;   p += E_ * CAP_;
  int* cnt = (int*)p;   p += 16;
  float* xin = p;  p += (size_t)E_ * CAP_ * D_;
  float* qb = p;   p += (size_t)4 * CAP_ * D_;
  float* kb = p;   p += (size_t)4 * CAP_ * D_;
  float* vb = p;   p += (size_t)4 * CAP_ * D_;
  float* ao = p;   p += (size_t)4 * CAP_ * D_;
  float* eo = p;   p += (size_t)E_ * CAP_ * D_;
  float* mid = qb;  // aliases qb..ao (64MB), used only after O-proj is done

  embed_kernel<<<T_, 256, 0, stream>>>(ids, embed_w, hA);
  float* cur = hA;
  float* nxt = hB;
  for (int hop = 0; hop < HOPS_; ++hop) {
    router_kernel<<<T_, 64, 0, stream>>>(cur, router_w + (size_t)hop * 9 * D_, probs, gmask);
    zero_kernel<<<16, 256, 0, stream>>>(rho, cnt);
    select_kernel<<<dim3(16, 8), 256, 0, stream>>>(gmask, probs, idx, cnt, rho);
    gather_kernel<<<dim3(CAP_, E_), 256, 0, stream>>>(cur, idx, cnt, xin);
    // QKV fused: z = which*4 + g, 768 blocks
    gemm_qkv<<<dim3(D_ / BN, CAP_ / BM, 12), 256, 0, stream>>>(xin, wq, wk, wv, qb, kb, vb);
    rope_kernel<<<dim3(CAP_, 4), 256, 0, stream>>>(qb, kb, idx, cnt);
    flash_kernel<<<dim3(64, 16, 4), 256, 0, stream>>>(qb, kb, vb, ao);
    // O projection -> eo even slots
    gemm_split<0><<<dim3(D_ / BN, CAP_ / BM, 4), 256, 0, stream>>>(
        ao, wo, eo, D_, D_,
        (long)CAP_ * D_, (long)D_ * D_, (long)2 * CAP_ * D_);
    // FFN (after O-proj so mid can alias qb/kb/vb/ao)
    gemm_split<1><<<dim3(MLP_ / BN, CAP_ / BM, 4), 256, 0, stream>>>(
        xin + (size_t)CAP_ * D_, w1, mid, MLP_, D_,
        (long)2 * CAP_ * D_, (long)D_ * MLP_, (long)CAP_ * MLP_);
    gemm_split<0><<<dim3(D_ / BN, CAP_ / BM, 4), 256, 0, stream>>>(
        mid, w2, eo + (size_t)CAP_ * D_, D_, MLP_,
        (long)CAP_ * MLP_, (long)MLP_ * D_, (long)2 * CAP_ * D_);
    initnew_kernel<<<T_, 256, 0, stream>>>(cur, rho, nxt);
    scatter_kernel<<<dim3(CAP_, E_), 256, 0, stream>>>(eo, idx, cnt, probs, nxt);
    float* tmp = cur; cur = nxt; nxt = tmp;
  }
  rms_kernel<<<T_, 256, 0, stream>>>(cur, lnw, out);
}

// Round 3
// 2761.013 us; speedup vs baseline: 3.3156x; 1.6586x over previous
//
#include <hip/hip_runtime.h>
#include <math.h>

#define T_ 4096
#define D_ 1024
#define H_ 16
#define DH_ 64
#define E_ 8
#define CAP_ 1024
#define MLP_ 4096
#define HOPS_ 3

// ================================================================ embed
__global__ __launch_bounds__(256) void embed_kernel(
    const int* __restrict__ ids, const float* __restrict__ ew, float* __restrict__ h)
{
  const int t = blockIdx.x;
  const int id = ids[t];
  const int c = threadIdx.x * 4;
  *(float4*)(h + (size_t)t * D_ + c) = *(const float4*)(ew + (size_t)id * D_ + c);
}

// ================================================================ router
__global__ __launch_bounds__(64) void router_kernel(
    const float* __restrict__ h, const float* __restrict__ rw,
    float* __restrict__ probs, float* __restrict__ gmask)
{
  const int t = blockIdx.x;
  const int lane = threadIdx.x;
  __shared__ float hs[D_];
  #pragma unroll
  for (int j = 0; j < 4; ++j)
    *(float4*)&hs[lane * 4 + j * 256] = *(const float4*)(h + (size_t)t * D_ + lane * 4 + j * 256);
  __syncthreads();
  float l9[9];
  #pragma unroll
  for (int e = 0; e < 9; ++e) {
    float s = 0.0f;
    for (int i = lane; i < D_; i += 64) s += hs[i] * rw[e * D_ + i];
    #pragma unroll
    for (int off = 32; off > 0; off >>= 1) s += __shfl_down(s, off);
    l9[e] = s;
  }
  if (lane == 0) {
    float m = l9[0];
    #pragma unroll
    for (int e = 1; e < 9; ++e) m = fmaxf(m, l9[e]);
    float sum = 0.0f;
    float ex[9];
    #pragma unroll
    for (int e = 0; e < 9; ++e) { ex[e] = expf(l9[e] - m); sum += ex[e]; }
    const float inv = 1.0f / sum;
    int b1 = 0;
    #pragma unroll
    for (int e = 1; e < 9; ++e) if (l9[e] > l9[b1]) b1 = e;
    int b2 = (b1 == 0) ? 1 : 0;
    #pragma unroll
    for (int e = 0; e < 9; ++e) if (e != b1 && e != b2 && l9[e] > l9[b2]) b2 = e;
    #pragma unroll
    for (int e = 0; e < 8; ++e) {
      const float pe = ex[e] * inv;
      probs[t * 8 + e] = pe;
      gmask[(size_t)e * T_ + t] = (e == b1 || e == b2) ? pe : -1e30f;
    }
  }
}

// ================================================================ zero
__global__ __launch_bounds__(256) void zero_kernel(float* __restrict__ rho, int* __restrict__ cnt)
{
  const int i = blockIdx.x * 256 + threadIdx.x;
  if (i < T_) rho[i] = 0.0f;
  if (i < E_) cnt[i] = 0;
}

// ================================================================ capacity select (rank-based)
__global__ __launch_bounds__(256) void select_kernel(
    const float* __restrict__ gmask, const float* __restrict__ probs,
    int* __restrict__ idx, int* __restrict__ cnt, float* __restrict__ rho)
{
  __shared__ float row[T_];
  const int e = blockIdx.y;
  const int tid = threadIdx.x;
  const float* gr = gmask + (size_t)e * T_;
  #pragma unroll
  for (int j = 0; j < 16; ++j) row[tid + 256 * j] = gr[tid + 256 * j];
  __syncthreads();
  const int t = blockIdx.x * 256 + tid;
  const float g = row[t];
  if (g > -1e29f) {
    int rank = 0;
    for (int tt = 0; tt < T_; ++tt) {
      const float gg = row[tt];
      rank += (gg > g) || (gg == g && tt < t);
    }
    if (rank < CAP_) {
      const int pos = atomicAdd(&cnt[e], 1);
      idx[e * CAP_ + pos] = t;
      atomicAdd(&rho[t], probs[t * 8 + e]);
    }
  }
}

// ================================================================ gather
__global__ __launch_bounds__(256) void gather_kernel(
    const float* __restrict__ h, const int* __restrict__ idx, const int* __restrict__ cnt,
    float* __restrict__ xin)
{
  const int c = blockIdx.x, e = blockIdx.y;
  const int c4 = threadIdx.x * 4;
  float4* dst = (float4*)(xin + ((size_t)e * CAP_ + c) * D_ + c4);
  if (c < cnt[e]) {
    const int t = idx[e * CAP_ + c];
    *dst = *(const float4*)(h + (size_t)t * D_ + c4);
  } else {
    float4 z; z.x = z.y = z.z = z.w = 0.0f;
    *dst = z;
  }
}

// ================================================================ split-bf16 helpers
typedef __bf16 bf16x8 __attribute__((ext_vector_type(8)));
typedef float f32x4v __attribute__((ext_vector_type(4)));

union FragU { uint2 u2[2]; bf16x8 v; };

__device__ __forceinline__ unsigned pack_hi2(unsigned u0, unsigned u1)
{
  return (u0 >> 16) | (u1 & 0xFFFF0000u);
}

__device__ __forceinline__ void split8(const float4 a, const float4 b, FragU& h, FragU& l)
{
  const float f[8] = {a.x, a.y, a.z, a.w, b.x, b.y, b.z, b.w};
  unsigned hu[8], lu[8];
  #pragma unroll
  for (int i = 0; i < 8; ++i) {
    const unsigned u = __float_as_uint(f[i]);
    const float lo = f[i] - __uint_as_float(u & 0xFFFF0000u);
    hu[i] = u; lu[i] = __float_as_uint(lo);
  }
  h.u2[0].x = pack_hi2(hu[0], hu[1]); h.u2[0].y = pack_hi2(hu[2], hu[3]);
  h.u2[1].x = pack_hi2(hu[4], hu[5]); h.u2[1].y = pack_hi2(hu[6], hu[7]);
  l.u2[0].x = pack_hi2(lu[0], lu[1]); l.u2[0].y = pack_hi2(lu[2], lu[3]);
  l.u2[1].x = pack_hi2(lu[4], lu[5]); l.u2[1].y = pack_hi2(lu[6], lu[7]);
}

// ================================================================ split-bf16 MFMA GEMM
#define BM 128
#define BN 128
#define BK 32
#define LDT 36

__device__ __forceinline__ float gelu_tanh(float x)
{
  const float x3 = x * x * x;
  return 0.5f * x * (1.0f + tanhf(0.7978845608028654f * (x + 0.044715f * x3)));
}

template <int EPI>
__device__ __forceinline__ void gemm_core(
    const float* __restrict__ A, const float* __restrict__ B, float* __restrict__ C,
    int N, int K)
{
  __shared__ unsigned short Ah[BM * LDT];
  __shared__ unsigned short Al[BM * LDT];
  __shared__ unsigned short Bh[BN * LDT];
  __shared__ unsigned short Bl[BN * LDT];

  const int tid = threadIdx.x;
  const int lane = tid & 63;
  const int w = tid >> 6;
  const int wm = w >> 1, wn = w & 1;
  const int m0 = blockIdx.y * BM;
  const int n0 = blockIdx.x * BN;
  const int q = lane >> 4;
  const int l15 = lane & 15;

  const int a_mo = tid >> 3;
  const int a_kq = (tid & 7) * 4;
  const int b_n = tid & 127;
  const int b_kh = (tid >> 7) * 16;

  f32x4v acc[4][4];
  #pragma unroll
  for (int i = 0; i < 4; ++i)
    #pragma unroll
    for (int j = 0; j < 4; ++j) { acc[i][j][0] = 0.f; acc[i][j][1] = 0.f; acc[i][j][2] = 0.f; acc[i][j][3] = 0.f; }

  float4 a_reg[4];
  float b_reg[16];

  const int nk = K / BK;
  #pragma unroll
  for (int t = 0; t < 4; ++t)
    a_reg[t] = *(const float4*)(A + (size_t)(m0 + t * 32 + a_mo) * K + a_kq);
  {
    const float* Bp = B + (size_t)b_kh * N + n0 + b_n;
    #pragma unroll
    for (int i = 0; i < 16; ++i) b_reg[i] = Bp[(size_t)i * N];
  }

  for (int kt = 0; kt < nk; ++kt) {
    __syncthreads();
    #pragma unroll
    for (int t = 0; t < 4; ++t) {
      const int m = t * 32 + a_mo;
      const unsigned u0 = __float_as_uint(a_reg[t].x);
      const unsigned u1 = __float_as_uint(a_reg[t].y);
      const unsigned u2 = __float_as_uint(a_reg[t].z);
      const unsigned u3 = __float_as_uint(a_reg[t].w);
      const float l0 = a_reg[t].x - __uint_as_float(u0 & 0xFFFF0000u);
      const float l1 = a_reg[t].y - __uint_as_float(u1 & 0xFFFF0000u);
      const float l2 = a_reg[t].z - __uint_as_float(u2 & 0xFFFF0000u);
      const float l3 = a_reg[t].w - __uint_as_float(u3 & 0xFFFF0000u);
      uint2 hp, lp;
      hp.x = pack_hi2(u0, u1); hp.y = pack_hi2(u2, u3);
      lp.x = pack_hi2(__float_as_uint(l0), __float_as_uint(l1));
      lp.y = pack_hi2(__float_as_uint(l2), __float_as_uint(l3));
      *(uint2*)&Ah[m * LDT + a_kq] = hp;
      *(uint2*)&Al[m * LDT + a_kq] = lp;
    }
    #pragma unroll
    for (int i = 0; i < 4; ++i) {
      const float f0 = b_reg[4 * i + 0], f1 = b_reg[4 * i + 1];
      const float f2 = b_reg[4 * i + 2], f3 = b_reg[4 * i + 3];
      const unsigned u0 = __float_as_uint(f0);
      const unsigned u1 = __float_as_uint(f1);
      const unsigned u2 = __float_as_uint(f2);
      const unsigned u3 = __float_as_uint(f3);
      const float l0 = f0 - __uint_as_float(u0 & 0xFFFF0000u);
      const float l1 = f1 - __uint_as_float(u1 & 0xFFFF0000u);
      const float l2 = f2 - __uint_as_float(u2 & 0xFFFF0000u);
      const float l3 = f3 - __uint_as_float(u3 & 0xFFFF0000u);
      uint2 hp, lp;
      hp.x = pack_hi2(u0, u1); hp.y = pack_hi2(u2, u3);
      lp.x = pack_hi2(__float_as_uint(l0), __float_as_uint(l1));
      lp.y = pack_hi2(__float_as_uint(l2), __float_as_uint(l3));
      *(uint2*)&Bh[b_n * LDT + b_kh + 4 * i] = hp;
      *(uint2*)&Bl[b_n * LDT + b_kh + 4 * i] = lp;
    }
    if (kt + 1 < nk) {
      const int k0 = (kt + 1) * BK;
      #pragma unroll
      for (int t = 0; t < 4; ++t)
        a_reg[t] = *(const float4*)(A + (size_t)(m0 + t * 32 + a_mo) * K + k0 + a_kq);
      const float* Bp = B + (size_t)(k0 + b_kh) * N + n0 + b_n;
      #pragma unroll
      for (int i = 0; i < 16; ++i) b_reg[i] = Bp[(size_t)i * N];
    }
    __syncthreads();
    FragU fa_h[4], fa_l[4], fb_h[4], fb_l[4];
    #pragma unroll
    for (int i = 0; i < 4; ++i) {
      const int m = wm * 64 + i * 16 + l15;
      const unsigned short* pa = &Ah[m * LDT + q * 8];
      const unsigned short* pl = &Al[m * LDT + q * 8];
      fa_h[i].u2[0] = *(const uint2*)pa; fa_h[i].u2[1] = *(const uint2*)(pa + 4);
      fa_l[i].u2[0] = *(const uint2*)pl; fa_l[i].u2[1] = *(const uint2*)(pl + 4);
    }
    #pragma unroll
    for (int j = 0; j < 4; ++j) {
      const int n = wn * 64 + j * 16 + l15;
      const unsigned short* pb = &Bh[n * LDT + q * 8];
      const unsigned short* pl = &Bl[n * LDT + q * 8];
      fb_h[j].u2[0] = *(const uint2*)pb; fb_h[j].u2[1] = *(const uint2*)(pb + 4);
      fb_l[j].u2[0] = *(const uint2*)pl; fb_l[j].u2[1] = *(const uint2*)(pl + 4);
    }
    #pragma unroll
    for (int i = 0; i < 4; ++i)
      #pragma unroll
      for (int j = 0; j < 4; ++j) {
        acc[i][j] = __builtin_amdgcn_mfma_f32_16x16x32_bf16(fa_h[i].v, fb_h[j].v, acc[i][j], 0, 0, 0);
        acc[i][j] = __builtin_amdgcn_mfma_f32_16x16x32_bf16(fa_h[i].v, fb_l[j].v, acc[i][j], 0, 0, 0);
        acc[i][j] = __builtin_amdgcn_mfma_f32_16x16x32_bf16(fa_l[i].v, fb_h[j].v, acc[i][j], 0, 0, 0);
      }
  }
  #pragma unroll
  for (int i = 0; i < 4; ++i)
    #pragma unroll
    for (int j = 0; j < 4; ++j) {
      const int n = n0 + wn * 64 + j * 16 + l15;
      #pragma unroll
      for (int r = 0; r < 4; ++r) {
        const int m = m0 + wm * 64 + i * 16 + q * 4 + r;
        float v = acc[i][j][r];
        if (EPI == 1) v = gelu_tanh(v);
        C[(size_t)m * N + n] = v;
      }
    }
}

template <int EPI>
__global__ __launch_bounds__(256, 2) void gemm_split(
    const float* __restrict__ Abase, const float* __restrict__ Bbase, float* __restrict__ Cbase,
    int N, int K, long sA, long sB, long sC)
{
  const float* A = Abase + (size_t)blockIdx.z * (size_t)sA;
  const float* B = Bbase + (size_t)blockIdx.z * (size_t)sB;
  float* C = Cbase + (size_t)blockIdx.z * (size_t)sC;
  gemm_core<EPI>(A, B, C, N, K);
}

__global__ __launch_bounds__(256, 2) void gemm_qkv(
    const float* __restrict__ xin,
    const float* __restrict__ wq, const float* __restrict__ wk, const float* __restrict__ wv,
    float* __restrict__ qb, float* __restrict__ kb, float* __restrict__ vb)
{
  const int z = blockIdx.z;
  const int g = z & 3;
  const int which = z >> 2;
  const float* A = xin + (size_t)g * 2 * CAP_ * D_;
  const float* B = ((which == 0) ? wq : (which == 1) ? wk : wv) + (size_t)g * D_ * D_;
  float* C = ((which == 0) ? qb : (which == 1) ? kb : vb) + (size_t)g * CAP_ * D_;
  gemm_core<0>(A, B, C, D_, D_);
}

// ================================================================ RoPE
__global__ __launch_bounds__(256) void rope_kernel(
    float* __restrict__ q, float* __restrict__ k,
    const int* __restrict__ idx, const int* __restrict__ cnt)
{
  const int c = blockIdx.x, g = blockIdx.y;
  const int e = 2 * g;
  if (c >= cnt[e]) return;
  const int t = idx[e * CAP_ + c];
  const int tid = threadIdx.x;
  const int hh = tid >> 4;
  const int pp = tid & 15;
  const size_t base = ((size_t)g * CAP_ + c) * D_ + hh * DH_;
  const float tf = (float)t;
  #pragma unroll
  for (int u = 0; u < 2; ++u) {
    const int i = pp * 2 + u;
    const float invf = (float)::pow(10000.0, -(double)i / 32.0);
    const float ang = tf * invf;
    const float cs = (float)::cos((double)ang);
    const float sn = (float)::sin((double)ang);
    const float q0 = q[base + i], q1 = q[base + i + 32];
    q[base + i]      = q0 * cs - q1 * sn;
    q[base + i + 32] = q1 * cs + q0 * sn;
    const float k0 = k[base + i], k1 = k[base + i + 32];
    k[base + i]      = k0 * cs - k1 * sn;
    k[base + i + 32] = k1 * cs + k0 * sn;
  }
}

// ================================================================ MFMA flash attention
// Block: 128 queries x full 1024 keys for one (group, head). 4 waves, 32 q-rows/wave.
// Split-bf16 (hi+lo) QK^T and PV keep relative error ~2^-16 vs f32 reference.
#define FBQ 128
#define LDK 68   // shorts per K/V^T/P LDS row
#define LDQ 72   // f32 per Q staging row

__global__ __launch_bounds__(256, 2) void flash_mfma(
    const float* __restrict__ qg, const float* __restrict__ kg,
    const float* __restrict__ vg, float* __restrict__ og)
{
  const int g = blockIdx.z, hh = blockIdx.y, qt = blockIdx.x;
  const size_t base = (size_t)g * CAP_ * D_ + hh * DH_;
  const float* Q = qg + base;
  const float* Kp = kg + base;
  const float* Vp = vg + base;
  float* O = og + base;

  __shared__ __align__(16) char lds_raw[69632];
  unsigned short* Kh  = (unsigned short*)lds_raw;      // [key][d]   64*LDK
  unsigned short* Kl  = Kh  + 64 * LDK;
  unsigned short* Vth = Kl  + 64 * LDK;                // [d][key]
  unsigned short* Vtl = Vth + 64 * LDK;
  unsigned short* Ph  = Vtl + 64 * LDK;                // [qrow][key] FBQ*LDK
  unsigned short* Pl  = Ph  + FBQ * LDK;
  float* Qs = (float*)lds_raw;                         // phase-A alias [FBQ][LDQ]

  const int tid = threadIdx.x;
  const int lane = tid & 63;
  const int w = tid >> 6;
  const int quad = lane >> 4;
  const int l15 = lane & 15;

  // ---- phase A: stage Q f32, extract per-wave A-fragments (hi/lo), then free LDS
  #pragma unroll
  for (int it = 0; it < 8; ++it) {
    const int row = it * 16 + (tid >> 4);
    const int c4 = (tid & 15) * 4;
    *(float4*)&Qs[row * LDQ + c4] = *(const float4*)(Q + (size_t)(qt * FBQ + row) * D_ + c4);
  }
  __syncthreads();
  FragU qf[2][2][2];  // [rowset][kstep][hi/lo]
  #pragma unroll
  for (int rs = 0; rs < 2; ++rs)
    #pragma unroll
    for (int ks = 0; ks < 2; ++ks) {
      const float* p0 = &Qs[(w * 32 + rs * 16 + l15) * LDQ + ks * 32 + quad * 8];
      const float4 f0 = *(const float4*)p0;
      const float4 f1 = *(const float4*)(p0 + 4);
      split8(f0, f1, qf[rs][ks][0], qf[rs][ks][1]);
    }
  __syncthreads();

  f32x4v acc[2][4];  // [rowset][dtile]
  float m_r[2][4], l_r[2][4];
  #pragma unroll
  for (int rs = 0; rs < 2; ++rs)
    #pragma unroll
    for (int r = 0; r < 4; ++r) { m_r[rs][r] = -1e30f; l_r[rs][r] = 0.0f; }
  #pragma unroll
  for (int rs = 0; rs < 2; ++rs)
    #pragma unroll
    for (int dt = 0; dt < 4; ++dt) { acc[rs][dt][0] = 0.f; acc[rs][dt][1] = 0.f; acc[rs][dt][2] = 0.f; acc[rs][dt][3] = 0.f; }

  for (int kt = 0; kt < 16; ++kt) {
    __syncthreads();
    // ---- stage K [key][d] and V^T [d][key], split hi/lo
    #pragma unroll
    for (int it = 0; it < 4; ++it) {
      const int r = it * 16 + (tid >> 4);   // key within tile
      const int c4 = (tid & 15) * 4;        // d
      const float4 kv = *(const float4*)(Kp + (size_t)(kt * 64 + r) * D_ + c4);
      {
        const unsigned u0 = __float_as_uint(kv.x), u1 = __float_as_uint(kv.y);
        const unsigned u2 = __float_as_uint(kv.z), u3 = __float_as_uint(kv.w);
        const float l0 = kv.x - __uint_as_float(u0 & 0xFFFF0000u);
        const float l1 = kv.y - __uint_as_float(u1 & 0xFFFF0000u);
        const float l2 = kv.z - __uint_as_float(u2 & 0xFFFF0000u);
        const float l3 = kv.w - __uint_as_float(u3 & 0xFFFF0000u);
        uint2 hp, lp;
        hp.x = pack_hi2(u0, u1); hp.y = pack_hi2(u2, u3);
        lp.x = pack_hi2(__float_as_uint(l0), __float_as_uint(l1));
        lp.y = pack_hi2(__float_as_uint(l2), __float_as_uint(l3));
        *(uint2*)&Kh[r * LDK + c4] = hp;
        *(uint2*)&Kl[r * LDK + c4] = lp;
      }
      const float4 vv = *(const float4*)(Vp + (size_t)(kt * 64 + r) * D_ + c4);
      const float vf[4] = {vv.x, vv.y, vv.z, vv.w};
      #pragma unroll
      for (int u = 0; u < 4; ++u) {
        const unsigned uu = __float_as_uint(vf[u]);
        const float lo = vf[u] - __uint_as_float(uu & 0xFFFF0000u);
        Vth[(c4 + u) * LDK + r] = (unsigned short)(uu >> 16);
        Vtl[(c4 + u) * LDK + r] = (unsigned short)(__float_as_uint(lo) >> 16);
      }
    }
    __syncthreads();
    // ---- QK^T -> S fragments
    f32x4v sfr[2][4];
    #pragma unroll
    for (int rs = 0; rs < 2; ++rs)
      #pragma unroll
      for (int j = 0; j < 4; ++j) {
        f32x4v s; s[0] = 0.f; s[1] = 0.f; s[2] = 0.f; s[3] = 0.f;
        #pragma unroll
        for (int ks = 0; ks < 2; ++ks) {
          FragU kh, kl;
          const unsigned short* pk = &Kh[(j * 16 + l15) * LDK + ks * 32 + quad * 8];
          const unsigned short* pl = &Kl[(j * 16 + l15) * LDK + ks * 32 + quad * 8];
          kh.u2[0] = *(const uint2*)pk; kh.u2[1] = *(const uint2*)(pk + 4);
          kl.u2[0] = *(const uint2*)pl; kl.u2[1] = *(const uint2*)(pl + 4);
          s = __builtin_amdgcn_mfma_f32_16x16x32_bf16(qf[rs][ks][0].v, kh.v, s, 0, 0, 0);
          s = __builtin_amdgcn_mfma_f32_16x16x32_bf16(qf[rs][ks][0].v, kl.v, s, 0, 0, 0);
          s = __builtin_amdgcn_mfma_f32_16x16x32_bf16(qf[rs][ks][1].v, kh.v, s, 0, 0, 0);
        }
        sfr[rs][j] = s;
      }
    // ---- online softmax + write P (split) to LDS
    #pragma unroll
    for (int rs = 0; rs < 2; ++rs) {
      #pragma unroll
      for (int r = 0; r < 4; ++r) {
        float s0 = sfr[rs][0][r] * 0.125f;
        float s1 = sfr[rs][1][r] * 0.125f;
        float s2 = sfr[rs][2][r] * 0.125f;
        float s3 = sfr[rs][3][r] * 0.125f;
        float mx = fmaxf(fmaxf(s0, s1), fmaxf(s2, s3));
        #pragma unroll
        for (int o = 1; o < 16; o <<= 1) mx = fmaxf(mx, __shfl_xor(mx, o));
        const float nm = fmaxf(m_r[rs][r], mx);
        const float al = __expf(m_r[rs][r] - nm);
        m_r[rs][r] = nm;
        const float p0 = __expf(s0 - nm);
        const float p1 = __expf(s1 - nm);
        const float p2 = __expf(s2 - nm);
        const float p3 = __expf(s3 - nm);
        float rsum = p0 + p1 + p2 + p3;
        #pragma unroll
        for (int o = 1; o < 16; o <<= 1) rsum += __shfl_xor(rsum, o);
        l_r[rs][r] = l_r[rs][r] * al + rsum;
        #pragma unroll
        for (int dt = 0; dt < 4; ++dt) acc[rs][dt][r] *= al;
        const int row = w * 32 + rs * 16 + quad * 4 + r;
        const float pv[4] = {p0, p1, p2, p3};
        #pragma unroll
        for (int j = 0; j < 4; ++j) {
          const unsigned u = __float_as_uint(pv[j]);
          const float lo = pv[j] - __uint_as_float(u & 0xFFFF0000u);
          Ph[row * LDK + j * 16 + l15] = (unsigned short)(u >> 16);
          Pl[row * LDK + j * 16 + l15] = (unsigned short)(__float_as_uint(lo) >> 16);
        }
      }
    }
    __syncthreads();
    // ---- PV accumulate
    FragU pf[2][2][2];  // [rowset][kstep][hi/lo]
    #pragma unroll
    for (int rs = 0; rs < 2; ++rs)
      #pragma unroll
      for (int ks = 0; ks < 2; ++ks) {
        const unsigned short* ph = &Ph[(w * 32 + rs * 16 + l15) * LDK + ks * 32 + quad * 8];
        const unsigned short* pl = &Pl[(w * 32 + rs * 16 + l15) * LDK + ks * 32 + quad * 8];
        pf[rs][ks][0].u2[0] = *(const uint2*)ph; pf[rs][ks][0].u2[1] = *(const uint2*)(ph + 4);
        pf[rs][ks][1].u2[0] = *(const uint2*)pl; pf[rs][ks][1].u2[1] = *(const uint2*)(pl + 4);
      }
    #pragma unroll
    for (int dt = 0; dt < 4; ++dt)
      #pragma unroll
      for (int ks = 0; ks < 2; ++ks) {
        FragU vh, vl;
        const unsigned short* pv_ = &Vth[(dt * 16 + l15) * LDK + ks * 32 + quad * 8];
        const unsigned short* pl_ = &Vtl[(dt * 16 + l15) * LDK + ks * 32 + quad * 8];
        vh.u2[0] = *(const uint2*)pv_; vh.u2[1] = *(const uint2*)(pv_ + 4);
        vl.u2[0] = *(const uint2*)pl_; vl.u2[1] = *(const uint2*)(pl_ + 4);
        #pragma unroll
        for (int rs = 0; rs < 2; ++rs) {
          acc[rs][dt] = __builtin_amdgcn_mfma_f32_16x16x32_bf16(pf[rs][ks][0].v, vh.v, acc[rs][dt], 0, 0, 0);
          acc[rs][dt] = __builtin_amdgcn_mfma_f32_16x16x32_bf16(pf[rs][ks][0].v, vl.v, acc[rs][dt], 0, 0, 0);
          acc[rs][dt] = __builtin_amdgcn_mfma_f32_16x16x32_bf16(pf[rs][ks][1].v, vh.v, acc[rs][dt], 0, 0, 0);
        }
      }
  }
  // ---- epilogue
  #pragma unroll
  for (int rs = 0; rs < 2; ++rs)
    #pragma unroll
    for (int r = 0; r < 4; ++r) {
      const float inv = 1.0f / l_r[rs][r];
      const int row = qt * FBQ + w * 32 + rs * 16 + quad * 4 + r;
      #pragma unroll
      for (int dt = 0; dt < 4; ++dt)
        O[(size_t)row * D_ + dt * 16 + l15] = acc[rs][dt][r] * inv;
    }
}

// ================================================================ hnew = h*(1-rho)
__global__ __launch_bounds__(256) void initnew_kernel(
    const float* __restrict__ h, const float* __restrict__ rho, float* __restrict__ hn)
{
  const int t = blockIdx.x;
  const float f = 1.0f - rho[t];
  const int c = threadIdx.x * 4;
  float4 x = *(const float4*)(h + (size_t)t * D_ + c);
  x.x *= f; x.y *= f; x.z *= f; x.w *= f;
  *(float4*)(hn + (size_t)t * D_ + c) = x;
}

// ================================================================ scatter
__global__ __launch_bounds__(256) void scatter_kernel(
    const float* __restrict__ eo, const int* __restrict__ idx, const int* __restrict__ cnt,
    const float* __restrict__ probs, float* __restrict__ hn)
{
  const int c = blockIdx.x, e = blockIdx.y;
  if (c >= cnt[e]) return;
  const int t = idx[e * CAP_ + c];
  const float w = probs[t * 8 + e];
  const float* src = eo + ((size_t)e * CAP_ + c) * D_;
  float* dst = hn + (size_t)t * D_;
  const int c4 = threadIdx.x * 4;
  #pragma unroll
  for (int j = 0; j < 4; ++j) atomicAdd(dst + c4 + j, src[c4 + j] * w);
}

// ================================================================ RMS norm
__global__ __launch_bounds__(256) void rms_kernel(
    const float* __restrict__ h, const float* __restrict__ w, float* __restrict__ out)
{
  const int t = blockIdx.x;
  const int c = threadIdx.x * 4;
  const float4 x = *(const float4*)(h + (size_t)t * D_ + c);
  float ss = x.x * x.x + x.y * x.y + x.z * x.z + x.w * x.w;
  #pragma unroll
  for (int off = 32; off > 0; off >>= 1) ss += __shfl_down(ss, off);
  __shared__ float wsum[4];
  __shared__ float sscale;
  const int lane = threadIdx.x & 63, wv = threadIdx.x >> 6;
  if (lane == 0) wsum[wv] = ss;
  __syncthreads();
  if (threadIdx.x == 0) {
    const float s = wsum[0] + wsum[1] + wsum[2] + wsum[3];
    sscale = 1.0f / sqrtf(s * (1.0f / (float)D_) + 1e-6f);
  }
  __syncthreads();
  const float sc = sscale;
  const float4 w4 = *(const float4*)(w + c);
  float4 o;
  o.x = x.x * sc * w4.x; o.y = x.y * sc * w4.y; o.z = x.z * sc * w4.z; o.w = x.w * sc * w4.w;
  *(float4*)(out + (size_t)t * D_ + c) = o;
}

// ================================================================ host
extern "C" void kernel_launch(void* const* d_in, const int* in_sizes, int n_in,
                              void* d_out, int out_size, void* d_ws, size_t ws_size,
                              hipStream_t stream)
{
  (void)in_sizes; (void)n_in; (void)out_size; (void)ws_size;
  const int* ids = (const int*)d_in[0];
  const float* embed_w = (const float*)d_in[1];
  const float* router_w = (const float*)d_in[2];
  const float* wq = (const float*)d_in[3];
  const float* wk = (const float*)d_in[4];
  const float* wv = (const float*)d_in[5];
  const float* wo = (const float*)d_in[6];
  const float* w1 = (const float*)d_in[7];
  const float* w2 = (const float*)d_in[8];
  const float* lnw = (const float*)d_in[9];
  float* out = (float*)d_out;

  float* p = (float*)d_ws;
  const size_t TD = (size_t)T_ * D_;
  float* hA = p;    p += TD;
  float* hB = p;    p += TD;
  float* probs = p; p += (size_t)T_ * E_;
  float* gmask = p; p += (size_t)E_ * T_;
  float* rho = p;   p += T_;
  int* idx = (int*)p;   p += E_ * CAP_;
  int* cnt = (int*)p;   p += 16;
  float* xin = p;  p += (size_t)E_ * CAP_ * D_;
  float* qb = p;   p += (size_t)4 * CAP_ * D_;
  float* kb = p;   p += (size_t)4 * CAP_ * D_;
  float* vb = p;   p += (size_t)4 * CAP_ * D_;
  float* ao = p;   p += (size_t)4 * CAP_ * D_;
  float* eo = p;   p += (size_t)E_ * CAP_ * D_;
  float* mid = qb;  // aliases qb..ao, used only after O-proj

  embed_kernel<<<T_, 256, 0, stream>>>(ids, embed_w, hA);
  float* cur = hA;
  float* nxt = hB;
  for (int hop = 0; hop < HOPS_; ++hop) {
    router_kernel<<<T_, 64, 0, stream>>>(cur, router_w + (size_t)hop * 9 * D_, probs, gmask);
    zero_kernel<<<16, 256, 0, stream>>>(rho, cnt);
    select_kernel<<<dim3(16, 8), 256, 0, stream>>>(gmask, probs, idx, cnt, rho);
    gather_kernel<<<dim3(CAP_, E_), 256, 0, stream>>>(cur, idx, cnt, xin);
    gemm_qkv<<<dim3(D_ / BN, CAP_ / BM, 12), 256, 0, stream>>>(xin, wq, wk, wv, qb, kb, vb);
    rope_kernel<<<dim3(CAP_, 4), 256, 0, stream>>>(qb, kb, idx, cnt);
    flash_mfma<<<dim3(CAP_ / FBQ, 16, 4), 256, 0, stream>>>(qb, kb, vb, ao);
    gemm_split<0><<<dim3(D_ / BN, CAP_ / BM, 4), 256, 0, stream>>>(
        ao, wo, eo, D_, D_,
        (long)CAP_ * D_, (long)D_ * D_, (long)2 * CAP_ * D_);
    gemm_split<1><<<dim3(MLP_ / BN, CAP_ / BM, 4), 256, 0, stream>>>(
        xin + (size_t)CAP_ * D_, w1, mid, MLP_, D_,
        (long)2 * CAP_ * D_, (long)D_ * MLP_, (long)CAP_ * MLP_);
    gemm_split<0><<<dim3(D_ / BN, CAP_ / BM, 4), 256, 0, stream>>>(
        mid, w2, eo + (size_t)CAP_ * D_, D_, MLP_,
        (long)CAP_ * MLP_, (long)MLP_ * D_, (long)2 * CAP_ * D_);
    initnew_kernel<<<T_, 256, 0, stream>>>(cur, rho, nxt);
    scatter_kernel<<<dim3(CAP_, E_), 256, 0, stream>>>(eo, idx, cnt, probs, nxt);
    float* tmp = cur; cur = nxt; nxt = tmp;
  }
  rms_kernel<<<T_, 256, 0, stream>>>(cur, lnw, out);
}